// Round 4
// baseline (160.897 us; speedup 1.0000x reference)
//
#include <hip/hip_runtime.h>
#include <hip/hip_cooperative_groups.h>
#include <math.h>

namespace cg = cooperative_groups;

#define NTOK 2048
#define CDIM 128
#define HHEADS 8
#define HDIM 16
#define NQW 32
#define NKW 128
#define PADW 48
#define CPD 16
#define BT 8

__device__ __forceinline__ float sigmoid_(float z){ return 1.0f/(1.0f+__expf(-z)); }
__device__ __forceinline__ float rdlane(float v, int l){
    return __int_as_float(__builtin_amdgcn_readlane(__float_as_int(v), l));
}

// ---------------- Phase A body: AdaLN+QKV (bid<256) / pair bias (bid>=256) ----------------
// act_t/sn_t: 1280 floats each ([128][10]); part: 16384 floats ([8][2][8][128])
__device__ __forceinline__ void front_phase(
    const float* __restrict__ x, const float* __restrict__ s,
    const float* __restrict__ s_w,
    const float* __restrict__ gate_w, const float* __restrict__ gate_b,
    const float* __restrict__ skip_w,
    const float* __restrict__ q_w, const float* __restrict__ q_b,
    const float* __restrict__ k_w, const float* __restrict__ v_w,
    const float* __restrict__ pair, const float* __restrict__ pln_w,
    const float* __restrict__ pln_b, const float* __restrict__ pproj,
    float* __restrict__ qo, float* __restrict__ ko, float* __restrict__ vo,
    float* __restrict__ bias,
    float* __restrict__ act_t, float* __restrict__ sn_t, float* __restrict__ part,
    int bid, int tid)
{
    if (bid >= NTOK/BT) {
        // ---------------- pair-bias path: 2 items per thread ----------------
        #pragma unroll
        for (int rep = 0; rep < 2; ++rep) {
            const int idx = (bid - NTOK/BT) * 1024 + rep*512 + tid;   // [0, 2048*128)
            const int qg = idx >> 7;
            const int j  = idx & 127;
            const int ib = qg >> 5;
            const int qr = qg & 31;
            const int kg = (ib << 5) - PADW + j;
            float outh[HHEADS] = {0,0,0,0,0,0,0,0};
            if (kg >= 0 && kg < NTOK) {
                const float* p = pair + ((size_t)qg * NTOK + kg) * CPD;
                float buf[CPD];
                float sum = 0.f, ssq = 0.f;
                #pragma unroll
                for (int c = 0; c < CPD; c += 4) {
                    const float4 t4 = *(const float4*)(p + c);
                    buf[c+0]=t4.x; buf[c+1]=t4.y; buf[c+2]=t4.z; buf[c+3]=t4.w;
                    sum += t4.x+t4.y+t4.z+t4.w;
                    ssq += t4.x*t4.x+t4.y*t4.y+t4.z*t4.z+t4.w*t4.w;
                }
                const float m  = sum * (1.0f/CPD);
                const float vr = ssq * (1.0f/CPD) - m*m;
                const float rs = rsqrtf(vr + 1e-5f);
                #pragma unroll
                for (int c = 0; c < CPD; ++c) {
                    const float y = (buf[c]-m)*rs*pln_w[c] + pln_b[c];
                    #pragma unroll
                    for (int h = 0; h < HHEADS; ++h)
                        outh[h] = fmaf(y, pproj[c*HHEADS+h], outh[h]);
                }
            }
            float* bb = bias + ((size_t)(ib*HHEADS)*NQW + qr)*NKW + j;
            #pragma unroll
            for (int h = 0; h < HHEADS; ++h)
                bb[(size_t)h*NQW*NKW] = outh[h];
        }
        return;
    }

    // ---------------- AdaLN + QKV path ----------------
    const int tok0 = bid * BT;
    const int w = tid >> 6;      // wave 0..7
    const int L = tid & 63;

    {
        const float2 xv = *(const float2*)(x + (size_t)(tok0+w)*CDIM + 2*L);
        const float2 yv = *(const float2*)(s + (size_t)(tok0+w)*CDIM + 2*L);
        float sx = xv.x+xv.y, sxx = xv.x*xv.x+xv.y*xv.y;
        float sy = yv.x+yv.y, syy = yv.x*yv.x+yv.y*yv.y;
        #pragma unroll
        for (int m = 1; m < 64; m <<= 1) {
            sx  += __shfl_xor(sx,  m, 64);
            sxx += __shfl_xor(sxx, m, 64);
            sy  += __shfl_xor(sy,  m, 64);
            syy += __shfl_xor(syy, m, 64);
        }
        const float inv = 1.0f/128.0f;
        const float mx = sx*inv, vx = sxx*inv - mx*mx;
        const float my = sy*inv, vy = syy*inv - my*my;
        const float rx = rsqrtf(vx+1e-5f), ry = rsqrtf(vy+1e-5f);
        const float2 swv = *(const float2*)(s_w + 2*L);
        act_t[(2*L)*10 + w]   = (xv.x-mx)*rx;
        act_t[(2*L+1)*10 + w] = (xv.y-mx)*rx;
        sn_t[(2*L)*10 + w]    = (yv.x-my)*ry*swv.x;
        sn_t[(2*L+1)*10 + w]  = (yv.y-my)*ry*swv.y;
    }
    __syncthreads();                                   // (1)

    const int i0 = w * 16;
    float snr0 = sn_t[(i0 + (L>>3))*10 + (L&7)];
    float snr1 = sn_t[(i0 + 8 + (L>>3))*10 + (L&7)];

    // ---- gate/skip matvec over i-chunk ----
    float ag[8][2] = {{0}}, as_[8][2] = {{0}};
    #pragma unroll
    for (int ii = 0; ii < 16; ++ii) {
        const float2 wg  = *(const float2*)(gate_w + (size_t)(i0+ii)*CDIM + 2*L);
        const float2 wsk = *(const float2*)(skip_w + (size_t)(i0+ii)*CDIM + 2*L);
        #pragma unroll
        for (int t = 0; t < 8; ++t) {
            const int v = ii*8 + t;
            const float a = rdlane((v < 64) ? snr0 : snr1, v & 63);
            ag[t][0]  = fmaf(a, wg.x,  ag[t][0]);
            ag[t][1]  = fmaf(a, wg.y,  ag[t][1]);
            as_[t][0] = fmaf(a, wsk.x, as_[t][0]);
            as_[t][1] = fmaf(a, wsk.y, as_[t][1]);
        }
    }
    #pragma unroll
    for (int t = 0; t < 8; ++t) {
        *(float2*)&part[((w*2+0)*8+t)*128 + 2*L] = make_float2(ag[t][0],  ag[t][1]);
        *(float2*)&part[((w*2+1)*8+t)*128 + 2*L] = make_float2(as_[t][0], as_[t][1]);
    }
    __syncthreads();                                   // (2)

    const int j  = tid & 127;
    const int tq = tid >> 7;
    {
        float zg[2] = {0,0}, zs[2] = {0,0};
        #pragma unroll
        for (int ww = 0; ww < 8; ++ww) {
            #pragma unroll
            for (int tt = 0; tt < 2; ++tt) {
                zg[tt] += part[((ww*2+0)*8 + 2*tq+tt)*128 + j];
                zs[tt] += part[((ww*2+1)*8 + 2*tq+tt)*128 + j];
            }
        }
        const float gb = gate_b[j];
        const float2 av = *(const float2*)&act_t[j*10 + 2*tq];
        const float a2x = sigmoid_(zg[0]+gb)*av.x + zs[0];
        const float a2y = sigmoid_(zg[1]+gb)*av.y + zs[1];
        *(float2*)&sn_t[j*10 + 2*tq] = make_float2(a2x, a2y);
    }
    __syncthreads();                                   // (3)

    // ---- q/k/v matvec over i-chunk ----
    float ar0 = sn_t[(i0 + (L>>3))*10 + (L&7)];
    float ar1 = sn_t[(i0 + 8 + (L>>3))*10 + (L&7)];
    float aq[8][2] = {{0}}, ak[8][2] = {{0}}, avv[8][2] = {{0}};
    #pragma unroll
    for (int ii = 0; ii < 16; ++ii) {
        const float2 wq = *(const float2*)(q_w + (size_t)(i0+ii)*CDIM + 2*L);
        const float2 wk = *(const float2*)(k_w + (size_t)(i0+ii)*CDIM + 2*L);
        const float2 wv = *(const float2*)(v_w + (size_t)(i0+ii)*CDIM + 2*L);
        #pragma unroll
        for (int t = 0; t < 8; ++t) {
            const int v = ii*8 + t;
            const float a = rdlane((v < 64) ? ar0 : ar1, v & 63);
            aq[t][0]  = fmaf(a, wq.x, aq[t][0]);
            aq[t][1]  = fmaf(a, wq.y, aq[t][1]);
            ak[t][0]  = fmaf(a, wk.x, ak[t][0]);
            ak[t][1]  = fmaf(a, wk.y, ak[t][1]);
            avv[t][0] = fmaf(a, wv.x, avv[t][0]);
            avv[t][1] = fmaf(a, wv.y, avv[t][1]);
        }
    }
    #pragma unroll
    for (int t = 0; t < 8; ++t) {
        *(float2*)&part[((w*2+0)*8+t)*128 + 2*L] = make_float2(aq[t][0], aq[t][1]);
        *(float2*)&part[((w*2+1)*8+t)*128 + 2*L] = make_float2(ak[t][0], ak[t][1]);
    }
    __syncthreads();                                   // (4)
    {
        float zq[2] = {0,0}, zk[2] = {0,0};
        #pragma unroll
        for (int ww = 0; ww < 8; ++ww) {
            #pragma unroll
            for (int tt = 0; tt < 2; ++tt) {
                zq[tt] += part[((ww*2+0)*8 + 2*tq+tt)*128 + j];
                zk[tt] += part[((ww*2+1)*8 + 2*tq+tt)*128 + j];
            }
        }
        const float qbj = q_b[j];
        #pragma unroll
        for (int tt = 0; tt < 2; ++tt) {
            const size_t row = (size_t)(tok0 + 2*tq + tt)*CDIM + j;
            qo[row] = zq[tt] + qbj;
            ko[row] = zk[tt];
        }
    }
    __syncthreads();                                   // (5)
    #pragma unroll
    for (int t = 0; t < 8; ++t)
        *(float2*)&part[((w*2+0)*8+t)*128 + 2*L] = make_float2(avv[t][0], avv[t][1]);
    __syncthreads();                                   // (6)
    {
        float zv[2] = {0,0};
        #pragma unroll
        for (int ww = 0; ww < 8; ++ww) {
            #pragma unroll
            for (int tt = 0; tt < 2; ++tt)
                zv[tt] += part[((ww*2+0)*8 + 2*tq+tt)*128 + j];
        }
        #pragma unroll
        for (int tt = 0; tt < 2; ++tt)
            vo[(size_t)(tok0 + 2*tq + tt)*CDIM + j] = zv[tt];
    }
}

// ---------------- Phase B body: local-window attention, one (ib,h) unit ----------------
// khs: 2560 floats [128][20]; vts: 2112 [16][132]; Pms: 4224 [32][132]
// Barriers unconditional; work guarded by 'act' (coop path runs with 512-thr blocks).
__device__ __forceinline__ void attn_phase(
    const float* __restrict__ qi, const float* __restrict__ ki,
    const float* __restrict__ vi, const float* __restrict__ bias,
    float* __restrict__ o,
    float* __restrict__ khs, float* __restrict__ vts, float* __restrict__ Pms,
    int ib, int h, int t, bool act)
{
    if (act) {   // stage: K row-major padded, V transposed
        const int jr  = t >> 1;
        const int d08 = (t & 1) * 8;
        const int kg  = ib*NQW - PADW + jr;
        float4 k0 = {0,0,0,0}, k1 = {0,0,0,0};
        float4 v0 = {0,0,0,0}, v1 = {0,0,0,0};
        if (kg >= 0 && kg < NTOK) {
            const float* sk = ki + (size_t)kg*CDIM + h*HDIM + d08;
            const float* sv = vi + (size_t)kg*CDIM + h*HDIM + d08;
            k0 = *(const float4*)sk;  k1 = *(const float4*)(sk+4);
            v0 = *(const float4*)sv;  v1 = *(const float4*)(sv+4);
        }
        *(float4*)&khs[jr*20 + d08]     = k0;
        *(float4*)&khs[jr*20 + d08 + 4] = k1;
        vts[(d08+0)*132 + jr] = v0.x;
        vts[(d08+1)*132 + jr] = v0.y;
        vts[(d08+2)*132 + jr] = v0.z;
        vts[(d08+3)*132 + jr] = v0.w;
        vts[(d08+4)*132 + jr] = v1.x;
        vts[(d08+5)*132 + jr] = v1.y;
        vts[(d08+6)*132 + jr] = v1.z;
        vts[(d08+7)*132 + jr] = v1.w;
    }
    __syncthreads();

    if (act) {   // QK^T + bias + softmax: thread = 2 q-rows x 8 k-cols
        const int rp = t >> 4;
        const int ln = t & 15;
        const int q0 = 2*rp;
        float4 qv[2][4];
        #pragma unroll
        for (int i = 0; i < 2; ++i) {
            const float4* qp = (const float4*)(qi + (size_t)(ib*NQW + q0 + i)*CDIM + h*HDIM);
            #pragma unroll
            for (int dq = 0; dq < 4; ++dq) qv[i][dq] = qp[dq];
        }
        const float* br = bias + ((size_t)(ib*HHEADS + h)*NQW + q0)*NKW;
        float acc[2][8];
        #pragma unroll
        for (int m2 = 0; m2 < 8; ++m2) {
            const int k = ln + 16*m2;
            const float4 c0 = *(const float4*)&khs[k*20];
            const float4 c1 = *(const float4*)&khs[k*20 + 4];
            const float4 c2 = *(const float4*)&khs[k*20 + 8];
            const float4 c3 = *(const float4*)&khs[k*20 + 12];
            #pragma unroll
            for (int i = 0; i < 2; ++i) {
                float sdot = qv[i][0].x*c0.x;
                sdot = fmaf(qv[i][0].y, c0.y, sdot);
                sdot = fmaf(qv[i][0].z, c0.z, sdot);
                sdot = fmaf(qv[i][0].w, c0.w, sdot);
                sdot = fmaf(qv[i][1].x, c1.x, sdot);
                sdot = fmaf(qv[i][1].y, c1.y, sdot);
                sdot = fmaf(qv[i][1].z, c1.z, sdot);
                sdot = fmaf(qv[i][1].w, c1.w, sdot);
                sdot = fmaf(qv[i][2].x, c2.x, sdot);
                sdot = fmaf(qv[i][2].y, c2.y, sdot);
                sdot = fmaf(qv[i][2].z, c2.z, sdot);
                sdot = fmaf(qv[i][2].w, c2.w, sdot);
                sdot = fmaf(qv[i][3].x, c3.x, sdot);
                sdot = fmaf(qv[i][3].y, c3.y, sdot);
                sdot = fmaf(qv[i][3].z, c3.z, sdot);
                sdot = fmaf(qv[i][3].w, c3.w, sdot);
                acc[i][m2] = sdot*0.25f + br[(size_t)i*NKW + k];
            }
        }
        #pragma unroll
        for (int i = 0; i < 2; ++i) {
            float mx = acc[i][0];
            #pragma unroll
            for (int m2 = 1; m2 < 8; ++m2) mx = fmaxf(mx, acc[i][m2]);
            mx = fmaxf(mx, __shfl_xor(mx, 1, 64));
            mx = fmaxf(mx, __shfl_xor(mx, 2, 64));
            mx = fmaxf(mx, __shfl_xor(mx, 4, 64));
            mx = fmaxf(mx, __shfl_xor(mx, 8, 64));
            float sm = 0.f;
            #pragma unroll
            for (int m2 = 0; m2 < 8; ++m2) { acc[i][m2] = __expf(acc[i][m2]-mx); sm += acc[i][m2]; }
            sm += __shfl_xor(sm, 1, 64);
            sm += __shfl_xor(sm, 2, 64);
            sm += __shfl_xor(sm, 4, 64);
            sm += __shfl_xor(sm, 8, 64);
            const float invs = 1.0f / sm;
            #pragma unroll
            for (int m2 = 0; m2 < 8; ++m2)
                Pms[(q0+i)*132 + ln + 16*m2] = acc[i][m2]*invs;
        }
    }
    __syncthreads();

    if (act) {   // PV: thread = (qr, d0); k-vectorized b128
        const int qr = t >> 3, d0 = t & 7;
        const float* pr  = &Pms[qr*132];
        const float* vp0 = &vts[d0*132];
        const float* vp1 = &vts[(d0+8)*132];
        float a0 = 0.f, a1 = 0.f;
        #pragma unroll
        for (int k4 = 0; k4 < 32; ++k4) {
            const float4 pm = *(const float4*)(pr  + 4*k4);
            const float4 u0 = *(const float4*)(vp0 + 4*k4);
            const float4 u1 = *(const float4*)(vp1 + 4*k4);
            a0 = fmaf(pm.x, u0.x, a0); a0 = fmaf(pm.y, u0.y, a0);
            a0 = fmaf(pm.z, u0.z, a0); a0 = fmaf(pm.w, u0.w, a0);
            a1 = fmaf(pm.x, u1.x, a1); a1 = fmaf(pm.y, u1.y, a1);
            a1 = fmaf(pm.z, u1.z, a1); a1 = fmaf(pm.w, u1.w, a1);
        }
        float* dst = o + (size_t)(ib*NQW + qr)*CDIM + h*HDIM;
        dst[d0]   = a0;
        dst[d0+8] = a1;
    }
}

// ---------------- Phase C body: output gating stack for 8 tokens ----------------
// b0_t/b1_t: 1280 floats ([128][10]); part: 8192 floats ([8][8][128])
__device__ __forceinline__ void back_phase(
    const float* __restrict__ oin, const float* __restrict__ gate_w,
    const float* __restrict__ proj_w, const float* __restrict__ out_w,
    const float* __restrict__ out_b, float* __restrict__ out,
    float* __restrict__ b0_t, float* __restrict__ b1_t, float* __restrict__ part,
    int tok0, int tid)
{
    const int w = tid >> 6, L = tid & 63;
    const int j = tid & 127, tq = tid >> 7;

    {
        const float2 ov = *(const float2*)(oin + (size_t)tok0*CDIM + 2*tid);
        const int e = 2*tid, c = e & 127, t = e >> 7;
        b0_t[c*10 + t]     = ov.x;
        b0_t[(c+1)*10 + t] = ov.y;
    }
    __syncthreads();

    const int i0 = w * 16;

    // ---- phase A: z = o @ gate_w ----
    {
        const float r0 = b0_t[(i0 + (L>>3))*10 + (L&7)];
        const float r1 = b0_t[(i0 + 8 + (L>>3))*10 + (L&7)];
        float acc[8][2] = {{0}};
        #pragma unroll
        for (int ii = 0; ii < 16; ++ii) {
            const float2 wv = *(const float2*)(gate_w + (size_t)(i0+ii)*CDIM + 2*L);
            #pragma unroll
            for (int t = 0; t < 8; ++t) {
                const int v = ii*8 + t;
                const float a = rdlane((v < 64) ? r0 : r1, v & 63);
                acc[t][0] = fmaf(a, wv.x, acc[t][0]);
                acc[t][1] = fmaf(a, wv.y, acc[t][1]);
            }
        }
        #pragma unroll
        for (int t = 0; t < 8; ++t)
            *(float2*)&part[(w*8+t)*128 + 2*L] = make_float2(acc[t][0], acc[t][1]);
    }
    __syncthreads();
    {
        float z[2] = {0,0};
        #pragma unroll
        for (int ww = 0; ww < 8; ++ww) {
            z[0] += part[(ww*8 + 2*tq)*128 + j];
            z[1] += part[(ww*8 + 2*tq+1)*128 + j];
        }
        const float2 ov = *(const float2*)&b0_t[j*10 + 2*tq];
        *(float2*)&b1_t[j*10 + 2*tq] = make_float2(sigmoid_(z[0])*ov.x, sigmoid_(z[1])*ov.y);
    }
    __syncthreads();

    // ---- phase B: t2 = g @ proj_w ----
    {
        const float r0 = b1_t[(i0 + (L>>3))*10 + (L&7)];
        const float r1 = b1_t[(i0 + 8 + (L>>3))*10 + (L&7)];
        float acc[8][2] = {{0}};
        #pragma unroll
        for (int ii = 0; ii < 16; ++ii) {
            const float2 wv = *(const float2*)(proj_w + (size_t)(i0+ii)*CDIM + 2*L);
            #pragma unroll
            for (int t = 0; t < 8; ++t) {
                const int v = ii*8 + t;
                const float a = rdlane((v < 64) ? r0 : r1, v & 63);
                acc[t][0] = fmaf(a, wv.x, acc[t][0]);
                acc[t][1] = fmaf(a, wv.y, acc[t][1]);
            }
        }
        #pragma unroll
        for (int t = 0; t < 8; ++t)
            *(float2*)&part[(w*8+t)*128 + 2*L] = make_float2(acc[t][0], acc[t][1]);
    }
    __syncthreads();
    float t2v[2];
    {
        float z[2] = {0,0};
        #pragma unroll
        for (int ww = 0; ww < 8; ++ww) {
            z[0] += part[(ww*8 + 2*tq)*128 + j];
            z[1] += part[(ww*8 + 2*tq+1)*128 + j];
        }
        t2v[0] = z[0]; t2v[1] = z[1];
        *(float2*)&b0_t[j*10 + 2*tq] = make_float2(z[0], z[1]);
    }
    __syncthreads();

    // ---- phase C: z3 = t2 @ out_w ; out = sigmoid(z3+b)*t2 ----
    {
        const float r0 = b0_t[(i0 + (L>>3))*10 + (L&7)];
        const float r1 = b0_t[(i0 + 8 + (L>>3))*10 + (L&7)];
        float acc[8][2] = {{0}};
        #pragma unroll
        for (int ii = 0; ii < 16; ++ii) {
            const float2 wv = *(const float2*)(out_w + (size_t)(i0+ii)*CDIM + 2*L);
            #pragma unroll
            for (int t = 0; t < 8; ++t) {
                const int v = ii*8 + t;
                const float a = rdlane((v < 64) ? r0 : r1, v & 63);
                acc[t][0] = fmaf(a, wv.x, acc[t][0]);
                acc[t][1] = fmaf(a, wv.y, acc[t][1]);
            }
        }
        #pragma unroll
        for (int t = 0; t < 8; ++t)
            *(float2*)&part[(w*8+t)*128 + 2*L] = make_float2(acc[t][0], acc[t][1]);
    }
    __syncthreads();
    {
        float z[2] = {0,0};
        #pragma unroll
        for (int ww = 0; ww < 8; ++ww) {
            z[0] += part[(ww*8 + 2*tq)*128 + j];
            z[1] += part[(ww*8 + 2*tq+1)*128 + j];
        }
        const float ob = out_b[j];
        out[(size_t)(tok0 + 2*tq)*CDIM + j]     = sigmoid_(z[0]+ob)*t2v[0];
        out[(size_t)(tok0 + 2*tq + 1)*CDIM + j] = sigmoid_(z[1]+ob)*t2v[1];
    }
}

// ==================== Cooperative fused kernel: identical phase bodies ====================
// 512 blocks x 512 thr, 2 blocks/CU (LDS 74 KB, VGPR<=128). Two grid.syncs replace
// two kernel boundaries. Work->thread mapping identical to the 3-kernel path.
__global__ __launch_bounds__(512, 4) void k_fused(
    const float* __restrict__ x, const float* __restrict__ s,
    const float* __restrict__ s_w,
    const float* __restrict__ gate_w, const float* __restrict__ gate_b,
    const float* __restrict__ skip_w,
    const float* __restrict__ q_w, const float* __restrict__ q_b,
    const float* __restrict__ k_w, const float* __restrict__ v_w,
    const float* __restrict__ pair, const float* __restrict__ pln_w,
    const float* __restrict__ pln_b, const float* __restrict__ pproj,
    const float* __restrict__ ogate_w, const float* __restrict__ oproj_w,
    const float* __restrict__ oout_w, const float* __restrict__ oout_b,
    float* __restrict__ qo, float* __restrict__ ko, float* __restrict__ vo,
    float* __restrict__ oo, float* __restrict__ bias, float* __restrict__ out)
{
    __shared__ float lds[18944];   // 74 KB: max(front 18944, attn 8896, back 10752)
    const int tid = threadIdx.x;
    const int bid = blockIdx.x;
    cg::grid_group grid = cg::this_grid();

    // Phase A: AdaLN+QKV (bid<256) / pair bias (bid>=256)
    front_phase(x, s, s_w, gate_w, gate_b, skip_w, q_w, q_b, k_w, v_w,
                pair, pln_w, pln_b, pproj, qo, ko, vo, bias,
                lds, lds + 1280, lds + 2560, bid, tid);

    grid.sync();

    // Phase B: attention unit = bid (ib = bid>>3, h = bid&7); threads 0..255 active
    attn_phase(qo, ko, vo, bias, oo,
               lds, lds + 2560, lds + 4672,
               bid >> 3, bid & 7, tid & 255, tid < 256);

    grid.sync();

    // Phase C: gating stack on blocks 0..255
    if (bid < NTOK/BT)
        back_phase(oo, ogate_w, oproj_w, oout_w, oout_b, out,
                   lds, lds + 1280, lds + 2560, bid * BT, tid);
}

// ==================== Fallback: verified R3 3-kernel path ====================
__global__ __launch_bounds__(512, 4) void k_front(
    const float* __restrict__ x, const float* __restrict__ s,
    const float* __restrict__ s_w,
    const float* __restrict__ gate_w, const float* __restrict__ gate_b,
    const float* __restrict__ skip_w,
    const float* __restrict__ q_w, const float* __restrict__ q_b,
    const float* __restrict__ k_w, const float* __restrict__ v_w,
    const float* __restrict__ pair, const float* __restrict__ pln_w,
    const float* __restrict__ pln_b, const float* __restrict__ pproj,
    float* __restrict__ qo, float* __restrict__ ko, float* __restrict__ vo,
    float* __restrict__ bias)
{
    __shared__ float act_t[1280];
    __shared__ float sn_t[1280];
    __shared__ float part[16384];
    front_phase(x, s, s_w, gate_w, gate_b, skip_w, q_w, q_b, k_w, v_w,
                pair, pln_w, pln_b, pproj, qo, ko, vo, bias,
                act_t, sn_t, part, blockIdx.x, threadIdx.x);
}

__global__ __launch_bounds__(256) void k_attn(
    const float* __restrict__ qi, const float* __restrict__ ki,
    const float* __restrict__ vi, const float* __restrict__ bias,
    float* __restrict__ o)
{
    __shared__ float khs[2560];
    __shared__ float vts[2112];
    __shared__ float Pms[4224];
    attn_phase(qi, ki, vi, bias, o, khs, vts, Pms,
               blockIdx.x, blockIdx.y, threadIdx.x, true);
}

__global__ __launch_bounds__(512) void k_back(
    const float* __restrict__ oin, const float* __restrict__ gate_w,
    const float* __restrict__ proj_w, const float* __restrict__ out_w,
    const float* __restrict__ out_b, float* __restrict__ out)
{
    __shared__ float b0_t[1280];
    __shared__ float b1_t[1280];
    __shared__ float part[8192];
    back_phase(oin, gate_w, proj_w, out_w, out_b, out,
               b0_t, b1_t, part, blockIdx.x * BT, threadIdx.x);
}

extern "C" void kernel_launch(void* const* d_in, const int* in_sizes, int n_in,
                              void* d_out, int out_size, void* d_ws, size_t ws_size,
                              hipStream_t stream) {
    (void)in_sizes; (void)n_in; (void)out_size; (void)ws_size;
    const float* x           = (const float*)d_in[0];
    const float* s           = (const float*)d_in[1];
    const float* pair        = (const float*)d_in[2];
    const float* adaln_s_w   = (const float*)d_in[3];
    const float* adaln_gate_w= (const float*)d_in[4];
    const float* adaln_gate_b= (const float*)d_in[5];
    const float* adaln_skip_w= (const float*)d_in[6];
    const float* q_w         = (const float*)d_in[7];
    const float* q_b         = (const float*)d_in[8];
    const float* k_w         = (const float*)d_in[9];
    const float* v_w         = (const float*)d_in[10];
    const float* pair_ln_w   = (const float*)d_in[11];
    const float* pair_ln_b   = (const float*)d_in[12];
    const float* pair_proj_w = (const float*)d_in[13];
    const float* gate_w      = (const float*)d_in[14];
    const float* attn_proj_w = (const float*)d_in[15];
    const float* out_w       = (const float*)d_in[16];
    const float* out_b       = (const float*)d_in[17];
    float* out = (float*)d_out;

    float* ws = (float*)d_ws;
    float* q_ws    = ws;                 // 2048*128
    float* k_ws    = ws + 262144;
    float* v_ws    = ws + 524288;
    float* o_ws    = ws + 786432;
    float* bias_ws = ws + 1048576;       // 64*8*32*128

    void* args[] = {
        (void*)&x, (void*)&s, (void*)&adaln_s_w, (void*)&adaln_gate_w,
        (void*)&adaln_gate_b, (void*)&adaln_skip_w, (void*)&q_w, (void*)&q_b,
        (void*)&k_w, (void*)&v_w, (void*)&pair, (void*)&pair_ln_w,
        (void*)&pair_ln_b, (void*)&pair_proj_w, (void*)&gate_w,
        (void*)&attn_proj_w, (void*)&out_w, (void*)&out_b,
        (void*)&q_ws, (void*)&k_ws, (void*)&v_ws, (void*)&o_ws,
        (void*)&bias_ws, (void*)&out
    };
    hipError_t err = hipLaunchCooperativeKernel((const void*)k_fused,
                                                dim3(512), dim3(512),
                                                args, 0, stream);
    if (err != hipSuccess) {
        (void)hipGetLastError();   // clear sticky error, use verified 3-kernel path
        k_front<<<NTOK/BT + (NTOK*NKW)/1024, 512, 0, stream>>>(
            x, s, adaln_s_w, adaln_gate_w, adaln_gate_b, adaln_skip_w,
            q_w, q_b, k_w, v_w, pair, pair_ln_w, pair_ln_b, pair_proj_w,
            q_ws, k_ws, v_ws, bias_ws);
        k_attn<<<dim3(NTOK/NQW, HHEADS), 256, 0, stream>>>(q_ws, k_ws, v_ws, bias_ws, o_ws);
        k_back<<<NTOK/BT, 512, 0, stream>>>(o_ws, gate_w, attn_proj_w, out_w, out_b, out);
    }
}

// Round 5
// 34.576 us; speedup vs baseline: 4.6534x; 4.6534x over previous
//
#include <hip/hip_runtime.h>
#include <math.h>

#define NTOK 2048
#define CDIM 128
#define HHEADS 8
#define HDIM 16
#define NQW 32
#define NKW 128
#define PADW 48
#define CPD 16
#define BT 8

__device__ __forceinline__ float sigmoid_(float z){ return 1.0f/(1.0f+__expf(-z)); }
__device__ __forceinline__ float rdlane(float v, int l){
    return __int_as_float(__builtin_amdgcn_readlane(__float_as_int(v), l));
}

// ============ Kernel 1: AdaLN+QKV (blocks 0..255) + pair bias (blocks 256..511) ============
// (verified R3 body: 74 KB LDS, 2 blocks/CU, one dispatch round)
__global__ __launch_bounds__(512, 4) void k_front(
    const float* __restrict__ x, const float* __restrict__ s,
    const float* __restrict__ s_w,
    const float* __restrict__ gate_w, const float* __restrict__ gate_b,
    const float* __restrict__ skip_w,
    const float* __restrict__ q_w, const float* __restrict__ q_b,
    const float* __restrict__ k_w, const float* __restrict__ v_w,
    const float* __restrict__ pair, const float* __restrict__ pln_w,
    const float* __restrict__ pln_b, const float* __restrict__ pproj,
    float* __restrict__ qo, float* __restrict__ ko, float* __restrict__ vo,
    float* __restrict__ bias)
{
    __shared__ float act_t[CDIM][10];          // [channel][token], padded
    __shared__ float sn_t[CDIM][10];           // sn, later a2
    __shared__ float part[8][2][BT][CDIM];     // 64 KB partials (2 slots, reused)
    const int tid = threadIdx.x;
    const int bid = blockIdx.x;

    if (bid >= NTOK/BT) {
        // ---------------- pair-bias path: 2 items per thread ----------------
        #pragma unroll
        for (int rep = 0; rep < 2; ++rep) {
            const int idx = (bid - NTOK/BT) * 1024 + rep*512 + tid;   // [0, 2048*128)
            const int qg = idx >> 7;
            const int j  = idx & 127;
            const int ib = qg >> 5;
            const int qr = qg & 31;
            const int kg = (ib << 5) - PADW + j;
            float outh[HHEADS] = {0,0,0,0,0,0,0,0};
            if (kg >= 0 && kg < NTOK) {
                const float* p = pair + ((size_t)qg * NTOK + kg) * CPD;
                float buf[CPD];
                float sum = 0.f, ssq = 0.f;
                #pragma unroll
                for (int c = 0; c < CPD; c += 4) {
                    const float4 t4 = *(const float4*)(p + c);
                    buf[c+0]=t4.x; buf[c+1]=t4.y; buf[c+2]=t4.z; buf[c+3]=t4.w;
                    sum += t4.x+t4.y+t4.z+t4.w;
                    ssq += t4.x*t4.x+t4.y*t4.y+t4.z*t4.z+t4.w*t4.w;
                }
                const float m  = sum * (1.0f/CPD);
                const float vr = ssq * (1.0f/CPD) - m*m;
                const float rs = rsqrtf(vr + 1e-5f);
                #pragma unroll
                for (int c = 0; c < CPD; ++c) {
                    const float y = (buf[c]-m)*rs*pln_w[c] + pln_b[c];
                    #pragma unroll
                    for (int h = 0; h < HHEADS; ++h)
                        outh[h] = fmaf(y, pproj[c*HHEADS+h], outh[h]);
                }
            }
            float* bb = bias + ((size_t)(ib*HHEADS)*NQW + qr)*NKW + j;
            #pragma unroll
            for (int h = 0; h < HHEADS; ++h)
                bb[(size_t)h*NQW*NKW] = outh[h];
        }
        return;
    }

    // ---------------- AdaLN + QKV path ----------------
    const int tok0 = bid * BT;
    const int w = tid >> 6;      // wave 0..7
    const int L = tid & 63;

    {
        const float2 xv = *(const float2*)(x + (size_t)(tok0+w)*CDIM + 2*L);
        const float2 yv = *(const float2*)(s + (size_t)(tok0+w)*CDIM + 2*L);
        float sx = xv.x+xv.y, sxx = xv.x*xv.x+xv.y*xv.y;
        float sy = yv.x+yv.y, syy = yv.x*yv.x+yv.y*yv.y;
        #pragma unroll
        for (int m = 1; m < 64; m <<= 1) {
            sx  += __shfl_xor(sx,  m, 64);
            sxx += __shfl_xor(sxx, m, 64);
            sy  += __shfl_xor(sy,  m, 64);
            syy += __shfl_xor(syy, m, 64);
        }
        const float inv = 1.0f/128.0f;
        const float mx = sx*inv, vx = sxx*inv - mx*mx;
        const float my = sy*inv, vy = syy*inv - my*my;
        const float rx = rsqrtf(vx+1e-5f), ry = rsqrtf(vy+1e-5f);
        const float2 swv = *(const float2*)(s_w + 2*L);
        act_t[2*L][w]   = (xv.x-mx)*rx;
        act_t[2*L+1][w] = (xv.y-mx)*rx;
        sn_t[2*L][w]    = (yv.x-my)*ry*swv.x;
        sn_t[2*L+1][w]  = (yv.y-my)*ry*swv.y;
    }
    __syncthreads();                                   // (1)

    const int i0 = w * 16;
    float snr0 = sn_t[i0 + (L>>3)][L&7];
    float snr1 = sn_t[i0 + 8 + (L>>3)][L&7];

    // ---- gate/skip matvec over i-chunk ----
    float ag[8][2] = {{0}}, as_[8][2] = {{0}};
    #pragma unroll
    for (int ii = 0; ii < 16; ++ii) {
        const float2 wg  = *(const float2*)(gate_w + (size_t)(i0+ii)*CDIM + 2*L);
        const float2 wsk = *(const float2*)(skip_w + (size_t)(i0+ii)*CDIM + 2*L);
        #pragma unroll
        for (int t = 0; t < 8; ++t) {
            const int v = ii*8 + t;
            const float a = rdlane((v < 64) ? snr0 : snr1, v & 63);
            ag[t][0]  = fmaf(a, wg.x,  ag[t][0]);
            ag[t][1]  = fmaf(a, wg.y,  ag[t][1]);
            as_[t][0] = fmaf(a, wsk.x, as_[t][0]);
            as_[t][1] = fmaf(a, wsk.y, as_[t][1]);
        }
    }
    #pragma unroll
    for (int t = 0; t < 8; ++t) {
        *(float2*)&part[w][0][t][2*L] = make_float2(ag[t][0],  ag[t][1]);
        *(float2*)&part[w][1][t][2*L] = make_float2(as_[t][0], as_[t][1]);
    }
    __syncthreads();                                   // (2)

    const int j  = tid & 127;
    const int tq = tid >> 7;
    {
        float zg[2] = {0,0}, zs[2] = {0,0};
        #pragma unroll
        for (int ww = 0; ww < 8; ++ww) {
            #pragma unroll
            for (int tt = 0; tt < 2; ++tt) {
                zg[tt] += part[ww][0][2*tq+tt][j];
                zs[tt] += part[ww][1][2*tq+tt][j];
            }
        }
        const float gb = gate_b[j];
        const float2 av = *(const float2*)&act_t[j][2*tq];
        const float a2x = sigmoid_(zg[0]+gb)*av.x + zs[0];
        const float a2y = sigmoid_(zg[1]+gb)*av.y + zs[1];
        *(float2*)&sn_t[j][2*tq] = make_float2(a2x, a2y);
    }
    __syncthreads();                                   // (3)

    // ---- q/k/v matvec over i-chunk ----
    float ar0 = sn_t[i0 + (L>>3)][L&7];
    float ar1 = sn_t[i0 + 8 + (L>>3)][L&7];
    float aq[8][2] = {{0}}, ak[8][2] = {{0}}, avv[8][2] = {{0}};
    #pragma unroll
    for (int ii = 0; ii < 16; ++ii) {
        const float2 wq = *(const float2*)(q_w + (size_t)(i0+ii)*CDIM + 2*L);
        const float2 wk = *(const float2*)(k_w + (size_t)(i0+ii)*CDIM + 2*L);
        const float2 wv = *(const float2*)(v_w + (size_t)(i0+ii)*CDIM + 2*L);
        #pragma unroll
        for (int t = 0; t < 8; ++t) {
            const int v = ii*8 + t;
            const float a = rdlane((v < 64) ? ar0 : ar1, v & 63);
            aq[t][0]  = fmaf(a, wq.x, aq[t][0]);
            aq[t][1]  = fmaf(a, wq.y, aq[t][1]);
            ak[t][0]  = fmaf(a, wk.x, ak[t][0]);
            ak[t][1]  = fmaf(a, wk.y, ak[t][1]);
            avv[t][0] = fmaf(a, wv.x, avv[t][0]);
            avv[t][1] = fmaf(a, wv.y, avv[t][1]);
        }
    }
    #pragma unroll
    for (int t = 0; t < 8; ++t) {
        *(float2*)&part[w][0][t][2*L] = make_float2(aq[t][0], aq[t][1]);
        *(float2*)&part[w][1][t][2*L] = make_float2(ak[t][0], ak[t][1]);
    }
    __syncthreads();                                   // (4)
    {
        float zq[2] = {0,0}, zk[2] = {0,0};
        #pragma unroll
        for (int ww = 0; ww < 8; ++ww) {
            #pragma unroll
            for (int tt = 0; tt < 2; ++tt) {
                zq[tt] += part[ww][0][2*tq+tt][j];
                zk[tt] += part[ww][1][2*tq+tt][j];
            }
        }
        const float qbj = q_b[j];
        #pragma unroll
        for (int tt = 0; tt < 2; ++tt) {
            const size_t row = (size_t)(tok0 + 2*tq + tt)*CDIM + j;
            qo[row] = zq[tt] + qbj;
            ko[row] = zk[tt];
        }
    }
    __syncthreads();                                   // (5)
    #pragma unroll
    for (int t = 0; t < 8; ++t)
        *(float2*)&part[w][0][t][2*L] = make_float2(avv[t][0], avv[t][1]);
    __syncthreads();                                   // (6)
    {
        float zv[2] = {0,0};
        #pragma unroll
        for (int ww = 0; ww < 8; ++ww) {
            #pragma unroll
            for (int tt = 0; tt < 2; ++tt)
                zv[tt] += part[ww][0][2*tq+tt][j];
        }
        #pragma unroll
        for (int tt = 0; tt < 2; ++tt)
            vo[(size_t)(tok0 + 2*tq + tt)*CDIM + j] = zv[tt];
    }
}

// ============ Kernel 2: local-window attention — P-in-registers PV ============
// K and V both staged row-major [128][20] (b128 writes, conflict-free: bank
// 20k mod 32 cycles all 8 bank-quads). One barrier. Thread (rp,ln) owns q-rows
// {2rp,2rp+1} and k-slices {ln+16*m2}; post-softmax P stays in registers; PV
// accumulates ov[2][16] over own k's; 4-step reduce-scatter over the 16-lane
// row group delivers column d=ln to each lane; 1/sum folded into the store.
__global__ __launch_bounds__(256) void k_attn(
    const float* __restrict__ qi, const float* __restrict__ ki,
    const float* __restrict__ vi, const float* __restrict__ bias,
    float* __restrict__ o)
{
    __shared__ float khs[NKW*20];        // 10.2 KB
    __shared__ float vhs[NKW*20];        // 10.2 KB
    const int ib = blockIdx.x;
    const int h  = blockIdx.y;
    const int t  = threadIdx.x;

    {   // stage: K and V row-major padded
        const int jr  = t >> 1;           // k-row 0..127
        const int d08 = (t & 1) * 8;      // d half 0 or 8
        const int kg  = ib*NQW - PADW + jr;
        float4 k0 = {0,0,0,0}, k1 = {0,0,0,0};
        float4 v0 = {0,0,0,0}, v1 = {0,0,0,0};
        if (kg >= 0 && kg < NTOK) {
            const float* sk = ki + (size_t)kg*CDIM + h*HDIM + d08;
            const float* sv = vi + (size_t)kg*CDIM + h*HDIM + d08;
            k0 = *(const float4*)sk;  k1 = *(const float4*)(sk+4);
            v0 = *(const float4*)sv;  v1 = *(const float4*)(sv+4);
        }
        *(float4*)&khs[jr*20 + d08]     = k0;
        *(float4*)&khs[jr*20 + d08 + 4] = k1;
        *(float4*)&vhs[jr*20 + d08]     = v0;
        *(float4*)&vhs[jr*20 + d08 + 4] = v1;
    }
    __syncthreads();

    const int rp = t >> 4;           // q-row pair 0..15
    const int ln = t & 15;           // k = ln + 16*m2
    const int q0 = 2*rp;

    // Q in registers (L1-broadcast global reads)
    float4 qv[2][4];
    #pragma unroll
    for (int i = 0; i < 2; ++i) {
        const float4* qp = (const float4*)(qi + (size_t)(ib*NQW + q0 + i)*CDIM + h*HDIM);
        #pragma unroll
        for (int dq = 0; dq < 4; ++dq) qv[i][dq] = qp[dq];
    }

    // ---- QK^T + bias ----
    const float* br = bias + ((size_t)(ib*HHEADS + h)*NQW + q0)*NKW;
    float p[2][8];
    #pragma unroll
    for (int m2 = 0; m2 < 8; ++m2) {
        const int k = ln + 16*m2;
        const float4 c0 = *(const float4*)&khs[k*20];
        const float4 c1 = *(const float4*)&khs[k*20 + 4];
        const float4 c2 = *(const float4*)&khs[k*20 + 8];
        const float4 c3 = *(const float4*)&khs[k*20 + 12];
        #pragma unroll
        for (int i = 0; i < 2; ++i) {
            float sdot = qv[i][0].x*c0.x;
            sdot = fmaf(qv[i][0].y, c0.y, sdot);
            sdot = fmaf(qv[i][0].z, c0.z, sdot);
            sdot = fmaf(qv[i][0].w, c0.w, sdot);
            sdot = fmaf(qv[i][1].x, c1.x, sdot);
            sdot = fmaf(qv[i][1].y, c1.y, sdot);
            sdot = fmaf(qv[i][1].z, c1.z, sdot);
            sdot = fmaf(qv[i][1].w, c1.w, sdot);
            sdot = fmaf(qv[i][2].x, c2.x, sdot);
            sdot = fmaf(qv[i][2].y, c2.y, sdot);
            sdot = fmaf(qv[i][2].z, c2.z, sdot);
            sdot = fmaf(qv[i][2].w, c2.w, sdot);
            sdot = fmaf(qv[i][3].x, c3.x, sdot);
            sdot = fmaf(qv[i][3].y, c3.y, sdot);
            sdot = fmaf(qv[i][3].z, c3.z, sdot);
            sdot = fmaf(qv[i][3].w, c3.w, sdot);
            p[i][m2] = sdot*0.25f + br[(size_t)i*NKW + k];
        }
    }

    // ---- softmax (unnormalized; 1/sum folded into store) ----
    float smv[2];
    #pragma unroll
    for (int i = 0; i < 2; ++i) {
        float mx = p[i][0];
        #pragma unroll
        for (int m2 = 1; m2 < 8; ++m2) mx = fmaxf(mx, p[i][m2]);
        mx = fmaxf(mx, __shfl_xor(mx, 1, 64));
        mx = fmaxf(mx, __shfl_xor(mx, 2, 64));
        mx = fmaxf(mx, __shfl_xor(mx, 4, 64));
        mx = fmaxf(mx, __shfl_xor(mx, 8, 64));
        float sm = 0.f;
        #pragma unroll
        for (int m2 = 0; m2 < 8; ++m2) { p[i][m2] = __expf(p[i][m2]-mx); sm += p[i][m2]; }
        sm += __shfl_xor(sm, 1, 64);
        sm += __shfl_xor(sm, 2, 64);
        sm += __shfl_xor(sm, 4, 64);
        sm += __shfl_xor(sm, 8, 64);
        smv[i] = sm;
    }

    // ---- PV: accumulate ov[2 q][16 d] over this thread's 8 k's ----
    float ov0[16], ov1[16];
    #pragma unroll
    for (int d = 0; d < 16; ++d) { ov0[d] = 0.f; ov1[d] = 0.f; }
    #pragma unroll
    for (int m2 = 0; m2 < 8; ++m2) {
        const int k = ln + 16*m2;
        const float4 a = *(const float4*)&vhs[k*20];
        const float4 b = *(const float4*)&vhs[k*20 + 4];
        const float4 c = *(const float4*)&vhs[k*20 + 8];
        const float4 d4 = *(const float4*)&vhs[k*20 + 12];
        const float p0 = p[0][m2], p1 = p[1][m2];
        ov0[0] = fmaf(p0, a.x, ov0[0]);  ov1[0] = fmaf(p1, a.x, ov1[0]);
        ov0[1] = fmaf(p0, a.y, ov0[1]);  ov1[1] = fmaf(p1, a.y, ov1[1]);
        ov0[2] = fmaf(p0, a.z, ov0[2]);  ov1[2] = fmaf(p1, a.z, ov1[2]);
        ov0[3] = fmaf(p0, a.w, ov0[3]);  ov1[3] = fmaf(p1, a.w, ov1[3]);
        ov0[4] = fmaf(p0, b.x, ov0[4]);  ov1[4] = fmaf(p1, b.x, ov1[4]);
        ov0[5] = fmaf(p0, b.y, ov0[5]);  ov1[5] = fmaf(p1, b.y, ov1[5]);
        ov0[6] = fmaf(p0, b.z, ov0[6]);  ov1[6] = fmaf(p1, b.z, ov1[6]);
        ov0[7] = fmaf(p0, b.w, ov0[7]);  ov1[7] = fmaf(p1, b.w, ov1[7]);
        ov0[8] = fmaf(p0, c.x, ov0[8]);  ov1[8] = fmaf(p1, c.x, ov1[8]);
        ov0[9] = fmaf(p0, c.y, ov0[9]);  ov1[9] = fmaf(p1, c.y, ov1[9]);
        ov0[10]= fmaf(p0, c.z, ov0[10]); ov1[10]= fmaf(p1, c.z, ov1[10]);
        ov0[11]= fmaf(p0, c.w, ov0[11]); ov1[11]= fmaf(p1, c.w, ov1[11]);
        ov0[12]= fmaf(p0, d4.x, ov0[12]); ov1[12]= fmaf(p1, d4.x, ov1[12]);
        ov0[13]= fmaf(p0, d4.y, ov0[13]); ov1[13]= fmaf(p1, d4.y, ov1[13]);
        ov0[14]= fmaf(p0, d4.z, ov0[14]); ov1[14]= fmaf(p1, d4.z, ov1[14]);
        ov0[15]= fmaf(p0, d4.w, ov0[15]); ov1[15]= fmaf(p1, d4.w, ov1[15]);
    }

    // ---- reduce-scatter over the 16-lane row group: lane ln ends with d=ln ----
    float e0, e1;
    {
        float r8a[8], r8b[8];
        #pragma unroll
        for (int j2 = 0; j2 < 8; ++j2) {
            const float lo0 = ov0[j2]   + __shfl_xor(ov0[j2],   8, 64);
            const float hi0 = ov0[j2+8] + __shfl_xor(ov0[j2+8], 8, 64);
            r8a[j2] = (ln & 8) ? hi0 : lo0;
            const float lo1 = ov1[j2]   + __shfl_xor(ov1[j2],   8, 64);
            const float hi1 = ov1[j2+8] + __shfl_xor(ov1[j2+8], 8, 64);
            r8b[j2] = (ln & 8) ? hi1 : lo1;
        }
        float r4a[4], r4b[4];
        #pragma unroll
        for (int j2 = 0; j2 < 4; ++j2) {
            const float lo0 = r8a[j2]   + __shfl_xor(r8a[j2],   4, 64);
            const float hi0 = r8a[j2+4] + __shfl_xor(r8a[j2+4], 4, 64);
            r4a[j2] = (ln & 4) ? hi0 : lo0;
            const float lo1 = r8b[j2]   + __shfl_xor(r8b[j2],   4, 64);
            const float hi1 = r8b[j2+4] + __shfl_xor(r8b[j2+4], 4, 64);
            r4b[j2] = (ln & 4) ? hi1 : lo1;
        }
        float r2a[2], r2b[2];
        #pragma unroll
        for (int j2 = 0; j2 < 2; ++j2) {
            const float lo0 = r4a[j2]   + __shfl_xor(r4a[j2],   2, 64);
            const float hi0 = r4a[j2+2] + __shfl_xor(r4a[j2+2], 2, 64);
            r2a[j2] = (ln & 2) ? hi0 : lo0;
            const float lo1 = r4b[j2]   + __shfl_xor(r4b[j2],   2, 64);
            const float hi1 = r4b[j2+2] + __shfl_xor(r4b[j2+2], 2, 64);
            r2b[j2] = (ln & 2) ? hi1 : lo1;
        }
        {
            const float lo0 = r2a[0] + __shfl_xor(r2a[0], 1, 64);
            const float hi0 = r2a[1] + __shfl_xor(r2a[1], 1, 64);
            e0 = (ln & 1) ? hi0 : lo0;
            const float lo1 = r2b[0] + __shfl_xor(r2b[0], 1, 64);
            const float hi1 = r2b[1] + __shfl_xor(r2b[1], 1, 64);
            e1 = (ln & 1) ? hi1 : lo1;
        }
    }

    float* dst = o + (size_t)(ib*NQW + q0)*CDIM + h*HDIM + ln;
    dst[0]    = e0 * (1.0f / smv[0]);
    dst[CDIM] = e1 * (1.0f / smv[1]);
}

// ============ Kernel 3: output gating stack (verified R3 body) ============
__global__ __launch_bounds__(512) void k_back(
    const float* __restrict__ oin, const float* __restrict__ gate_w,
    const float* __restrict__ proj_w, const float* __restrict__ out_w,
    const float* __restrict__ out_b, float* __restrict__ out)
{
    __shared__ float b0_t[CDIM][10];   // o, later t2
    __shared__ float b1_t[CDIM][10];   // gated
    __shared__ float part[8][BT][CDIM];
    const int tid = threadIdx.x;
    const int tok0 = blockIdx.x * BT;
    const int w = tid >> 6, L = tid & 63;
    const int j = tid & 127, tq = tid >> 7;

    {   // load o tile into [channel][token] layout
        const float2 ov = *(const float2*)(oin + (size_t)tok0*CDIM + 2*tid);
        const int e = 2*tid, c = e & 127, t = e >> 7;
        b0_t[c][t]   = ov.x;
        b0_t[c+1][t] = ov.y;
    }
    __syncthreads();

    const int i0 = w * 16;

    // ---- phase A: z = o @ gate_w ----
    {
        const float r0 = b0_t[i0 + (L>>3)][L&7];
        const float r1 = b0_t[i0 + 8 + (L>>3)][L&7];
        float acc[8][2] = {{0}};
        #pragma unroll
        for (int ii = 0; ii < 16; ++ii) {
            const float2 wv = *(const float2*)(gate_w + (size_t)(i0+ii)*CDIM + 2*L);
            #pragma unroll
            for (int t = 0; t < 8; ++t) {
                const int v = ii*8 + t;
                const float a = rdlane((v < 64) ? r0 : r1, v & 63);
                acc[t][0] = fmaf(a, wv.x, acc[t][0]);
                acc[t][1] = fmaf(a, wv.y, acc[t][1]);
            }
        }
        #pragma unroll
        for (int t = 0; t < 8; ++t)
            *(float2*)&part[w][t][2*L] = make_float2(acc[t][0], acc[t][1]);
    }
    __syncthreads();
    {   // reduce; g = sigmoid(z) * o -> b1_t
        float z[2] = {0,0};
        #pragma unroll
        for (int ww = 0; ww < 8; ++ww) {
            z[0] += part[ww][2*tq][j];
            z[1] += part[ww][2*tq+1][j];
        }
        const float2 ov = *(const float2*)&b0_t[j][2*tq];
        *(float2*)&b1_t[j][2*tq] = make_float2(sigmoid_(z[0])*ov.x, sigmoid_(z[1])*ov.y);
    }
    __syncthreads();

    // ---- phase B: t2 = g @ proj_w ----
    {
        const float r0 = b1_t[i0 + (L>>3)][L&7];
        const float r1 = b1_t[i0 + 8 + (L>>3)][L&7];
        float acc[8][2] = {{0}};
        #pragma unroll
        for (int ii = 0; ii < 16; ++ii) {
            const float2 wv = *(const float2*)(proj_w + (size_t)(i0+ii)*CDIM + 2*L);
            #pragma unroll
            for (int t = 0; t < 8; ++t) {
                const int v = ii*8 + t;
                const float a = rdlane((v < 64) ? r0 : r1, v & 63);
                acc[t][0] = fmaf(a, wv.x, acc[t][0]);
                acc[t][1] = fmaf(a, wv.y, acc[t][1]);
            }
        }
        #pragma unroll
        for (int t = 0; t < 8; ++t)
            *(float2*)&part[w][t][2*L] = make_float2(acc[t][0], acc[t][1]);
    }
    __syncthreads();
    float t2v[2];
    {   // reduce; keep t2 in regs, stash into b0_t for phase-C readlane source
        float z[2] = {0,0};
        #pragma unroll
        for (int ww = 0; ww < 8; ++ww) {
            z[0] += part[ww][2*tq][j];
            z[1] += part[ww][2*tq+1][j];
        }
        t2v[0] = z[0]; t2v[1] = z[1];
        *(float2*)&b0_t[j][2*tq] = make_float2(z[0], z[1]);
    }
    __syncthreads();

    // ---- phase C: z3 = t2 @ out_w ; out = sigmoid(z3+b)*t2 ----
    {
        const float r0 = b0_t[i0 + (L>>3)][L&7];
        const float r1 = b0_t[i0 + 8 + (L>>3)][L&7];
        float acc[8][2] = {{0}};
        #pragma unroll
        for (int ii = 0; ii < 16; ++ii) {
            const float2 wv = *(const float2*)(out_w + (size_t)(i0+ii)*CDIM + 2*L);
            #pragma unroll
            for (int t = 0; t < 8; ++t) {
                const int v = ii*8 + t;
                const float a = rdlane((v < 64) ? r0 : r1, v & 63);
                acc[t][0] = fmaf(a, wv.x, acc[t][0]);
                acc[t][1] = fmaf(a, wv.y, acc[t][1]);
            }
        }
        #pragma unroll
        for (int t = 0; t < 8; ++t)
            *(float2*)&part[w][t][2*L] = make_float2(acc[t][0], acc[t][1]);
    }
    __syncthreads();
    {
        float z[2] = {0,0};
        #pragma unroll
        for (int ww = 0; ww < 8; ++ww) {
            z[0] += part[ww][2*tq][j];
            z[1] += part[ww][2*tq+1][j];
        }
        const float ob = out_b[j];
        out[(size_t)(tok0 + 2*tq)*CDIM + j]     = sigmoid_(z[0]+ob)*t2v[0];
        out[(size_t)(tok0 + 2*tq + 1)*CDIM + j] = sigmoid_(z[1]+ob)*t2v[1];
    }
}

extern "C" void kernel_launch(void* const* d_in, const int* in_sizes, int n_in,
                              void* d_out, int out_size, void* d_ws, size_t ws_size,
                              hipStream_t stream) {
    (void)in_sizes; (void)n_in; (void)out_size; (void)ws_size;
    const float* x           = (const float*)d_in[0];
    const float* s           = (const float*)d_in[1];
    const float* pair        = (const float*)d_in[2];
    const float* adaln_s_w   = (const float*)d_in[3];
    const float* adaln_gate_w= (const float*)d_in[4];
    const float* adaln_gate_b= (const float*)d_in[5];
    const float* adaln_skip_w= (const float*)d_in[6];
    const float* q_w         = (const float*)d_in[7];
    const float* q_b         = (const float*)d_in[8];
    const float* k_w         = (const float*)d_in[9];
    const float* v_w         = (const float*)d_in[10];
    const float* pair_ln_w   = (const float*)d_in[11];
    const float* pair_ln_b   = (const float*)d_in[12];
    const float* pair_proj_w = (const float*)d_in[13];
    const float* gate_w      = (const float*)d_in[14];
    const float* attn_proj_w = (const float*)d_in[15];
    const float* out_w       = (const float*)d_in[16];
    const float* out_b       = (const float*)d_in[17];
    float* out = (float*)d_out;

    float* ws = (float*)d_ws;
    float* q_ws    = ws;                 // 2048*128
    float* k_ws    = ws + 262144;
    float* v_ws    = ws + 524288;
    float* o_ws    = ws + 786432;
    float* bias_ws = ws + 1048576;       // 64*8*32*128

    // 256 QKV blocks + 256 pair-bias blocks in one launch (one dispatch round at 2 blk/CU)
    k_front<<<NTOK/BT + (NTOK*NKW)/1024, 512, 0, stream>>>(
        x, s, adaln_s_w, adaln_gate_w, adaln_gate_b, adaln_skip_w,
        q_w, q_b, k_w, v_w, pair, pair_ln_w, pair_ln_b, pair_proj_w,
        q_ws, k_ws, v_ws, bias_ws);
    k_attn<<<dim3(NTOK/NQW, HHEADS), 256, 0, stream>>>(q_ws, k_ws, v_ws, bias_ws, o_ws);
    k_back<<<NTOK/BT, 512, 0, stream>>>(o_ws, gate_w, attn_proj_w, out_w, out_b, out);
}